// Round 3
// baseline (663.150 us; speedup 1.0000x reference)
//
#include <hip/hip_runtime.h>

typedef _Float16 half8 __attribute__((ext_vector_type(8)));
typedef __fp16   pk2   __attribute__((ext_vector_type(2)));
typedef float    f32x4 __attribute__((ext_vector_type(4)));

#define GLOBAL_AS __attribute__((address_space(1)))
#define LDS_AS    __attribute__((address_space(3)))

static constexpr int Bb = 32;
static constexpr int Nn = 2048;
static constexpr int Dd = 1024;
static constexpr int M  = Bb * Nn;   // 65536 rows of the big GEMM

// ---------------------------------------------------------------------------
// Packed operand layout (shared by prep kernels and gemm8):
// chunk = one (tile, half) = 128 rows/cols x 64 k of f16 = 16 KB, staged
// linearly by global_load_lds. Within a chunk, half8 unit u = q*128 + s
// (q = k-octet 0..7) holds logical row  r = s ^ (2*(q&3))  -- the XOR is the
// LDS bank swizzle, pre-baked into the GLOBAL layout (linear LDS dest +
// inverse-swizzled source + swizzled ds_read, per the both-sides rule).
// A_p chunks: [mtile(256)][t(16)][h(2)]   W1TT chunks: [et(4)][t(16)][h(2)]
// ---------------------------------------------------------------------------

// Kernel 1a: pack W1 (f32 [d][e]) -> swizzled f16 chunks.
__global__ void prep_w1(const float* __restrict__ W1, _Float16* __restrict__ W1TT) {
    int g = blockIdx.x * 256 + threadIdx.x;   // 131072 half8 units
    int chunk = g >> 10;                      // et*32 + t*2 + h
    int u = g & 1023;
    int q = u >> 7, sc = u & 127;
    int cl = sc ^ (2 * (q & 3));
    int et = chunk >> 5, t = (chunk >> 1) & 15, h = chunk & 1;
    int e  = et * 256 + h * 128 + cl;
    int k0 = t * 64 + q * 8;
    half8 hh;
#pragma unroll
    for (int j = 0; j < 8; ++j)
        hh[j] = (_Float16)W1[(size_t)(k0 + j) * Dd + e];
    *(half8*)(W1TT + (size_t)g * 8) = hh;
}

// Kernel 1b: convert+pack encoded (f32 [m][d]) -> swizzled f16 chunks.
// LDS-staged transpose keeps both the 256 MiB read and 128 MiB write coalesced.
__global__ void prep_enc(const float* __restrict__ A, _Float16* __restrict__ A_p) {
    __shared__ _Float16 T[128 * 64];          // 16 KB, slot-XOR banked
    const int c = blockIdx.x;                 // 8192 chunks
    const int tid = threadIdx.x;
    const int mtile = c >> 5, t = (c >> 1) & 15, h = c & 1;
    const int r = tid >> 1, kh = tid & 1;     // thread reads 128B of one row
    const float* src = A + (size_t)(mtile * 256 + h * 128 + r) * Dd + t * 64 + kh * 32;
    const int rx = r & 7;
#pragma unroll
    for (int i = 0; i < 4; ++i) {
        f32x4 a  = *(const f32x4*)(src + i * 8);
        f32x4 b2 = *(const f32x4*)(src + i * 8 + 4);
        half8 hh; pk2 p;
        p = __builtin_amdgcn_cvt_pkrtz(a.x, a.y);   hh[0] = p[0]; hh[1] = p[1];
        p = __builtin_amdgcn_cvt_pkrtz(a.z, a.w);   hh[2] = p[0]; hh[3] = p[1];
        p = __builtin_amdgcn_cvt_pkrtz(b2.x, b2.y); hh[4] = p[0]; hh[5] = p[1];
        p = __builtin_amdgcn_cvt_pkrtz(b2.z, b2.w); hh[6] = p[0]; hh[7] = p[1];
        *(half8*)(T + r * 64 + (((kh * 4 + i) ^ rx) * 8)) = hh;   // slot ^= r&7
    }
    __syncthreads();
    const size_t cb = (size_t)c * 8192;
#pragma unroll
    for (int i = 0; i < 4; ++i) {
        int u = i * 256 + tid;
        int q = u >> 7, sr = u & 127;
        int lr = sr ^ (2 * (q & 3));
        half8 hh = *(const half8*)(T + lr * 64 + ((q ^ (lr & 7)) * 8));
        *(half8*)(A_p + cb + (size_t)u * 8) = hh;  // fully coalesced 16B stores
    }
}

// ---------------------------------------------------------------------------
// Kernel 2: dec[b][e] = decoder_state[b] @ W2   (32x1024)
// ---------------------------------------------------------------------------
__global__ void dec_kernel(const float* __restrict__ ds, const float* __restrict__ W2,
                           float* __restrict__ dec) {
    __shared__ float part[4][64];
    int b = blockIdx.x, ech = blockIdx.y;
    int tid = threadIdx.x;
    int e = ech * 64 + (tid & 63);
    int dc = tid >> 6;
    float acc = 0.f;
#pragma unroll 4
    for (int d = dc * 256; d < dc * 256 + 256; ++d)
        acc += ds[b * Dd + d] * W2[(size_t)d * Dd + e];
    part[dc][tid & 63] = acc;
    __syncthreads();
    if (tid < 64)
        dec[b * Dd + e] = part[0][tid] + part[1][tid] + part[2][tid] + part[3][tid];
}

// ---------------------------------------------------------------------------
// Kernel 3: 256x256 tile, 8 waves, persistent over 2 mtiles (32 K-tiles, one
// continuous pipeline; A_p chunk index is LINEAR in the global tile counter).
// Uniform max-early staging cadence: each half-chunk staged the phase after
// its LDS slot frees -> stage-to-read distance = 7 phases for every chunk.
// Only TWO vmcnt gates per 8 phases (p4, p8), both VM(8): each retires loads
// issued >=4 phases earlier (HBM latency fully covered; in-flight 8 hc).
// Counted lgkm pacing: p1:4 p2:8 p3:8 p5:4 p6:8 p7:8 (ledger-derived).
// Per-mtile epilogue is LDS-free (u_part 16 partial slices), so the pipeline
// flows through the mtile boundary without draining.
// ---------------------------------------------------------------------------
#define BAR     asm volatile("s_barrier" ::: "memory")
#define LGKM(n) asm volatile("s_waitcnt lgkmcnt(" #n ")" ::: "memory")
#define VM(n)   asm volatile("s_waitcnt vmcnt(" #n ")" ::: "memory")

#define RD_A(dst, base) do { _Pragma("unroll") \
  for (int ks = 0; ks < 2; ++ks) { const int qb = ((ks * 4 + qq) * 128) * 8; \
    _Pragma("unroll") for (int m2 = 0; m2 < 4; ++m2) \
      dst[m2][ks] = *(const half8*)&lds[(base) + qb + (m2 * 32 + rA) * 8]; } } while (0)

#define RD_B(dst, base) do { _Pragma("unroll") \
  for (int ks = 0; ks < 2; ++ks) { const int qb = ((ks * 4 + qq) * 128) * 8; \
    _Pragma("unroll") for (int j2 = 0; j2 < 2; ++j2) \
      dst[j2][ks] = *(const half8*)&lds[(base) + qb + (j2 * 64 + rB) * 8]; } } while (0)

#define MFMAQ(A_, B_, ro, co) do { __builtin_amdgcn_s_setprio(1); \
  _Pragma("unroll") for (int m2 = 0; m2 < 4; ++m2) \
  _Pragma("unroll") for (int j2 = 0; j2 < 2; ++j2) { \
    acc[(ro) + m2][(co) + j2] = __builtin_amdgcn_mfma_f32_16x16x32_f16( \
        A_[m2][0], B_[j2][0], acc[(ro) + m2][(co) + j2], 0, 0, 0); \
    acc[(ro) + m2][(co) + j2] = __builtin_amdgcn_mfma_f32_16x16x32_f16( \
        A_[m2][1], B_[j2][1], acc[(ro) + m2][(co) + j2], 0, 0, 0); } \
  __builtin_amdgcn_s_setprio(0); } while (0)

__global__ __launch_bounds__(512) void gemm8(
    const _Float16* __restrict__ A_p, const _Float16* __restrict__ W1TT,
    const float* __restrict__ dec, const float* __restrict__ vt,
    float* __restrict__ u_part)          // [16][65536]  (et*4+wc slices)
{
    extern __shared__ _Float16 lds[];    // 65536 halfs = 128 KB

    const int g  = blockIdx.x;                   // 0..511
    const int wg = (g & 7) * 64 + (g >> 3);      // XCD-chunked swizzle (512%8==0)
    const int et   = wg & 3;                     // 4 consecutive wg share A
    const int mgrp = wg >> 2;                    // 0..127 -> mtiles {2m, 2m+1}
    const int m0 = mgrp * 2;

    const int tid  = threadIdx.x;
    const int lane = tid & 63, wid = tid >> 6;
    const int wr = wid >> 2, wc = wid & 3;
    const int qq = lane >> 4, l15 = lane & 15;
    const int l15s = l15 ^ (2 * qq);             // read-side bank swizzle
    const int rA = wr * 16 + l15s;
    const int rB = wc * 16 + l15s;

    f32x4 acc[8][4] = {};
    half8 a0[4][2], a1[4][2], b0[2][2], b1[2][2];

    // epilogue operands preloaded BEFORE the pipeline (keeps vmcnt clean;
    // b = m0>>3 is constant across the block's 2 mtiles: 2-aligned pair
    // cannot cross an 8-boundary).
    const int bb = m0 >> 3;
    float vtv[4], dcv[4];
#pragma unroll
    for (int nf = 0; nf < 4; ++nf) {
        int e = et * 256 + (nf >> 1) * 128 + (nf & 1) * 64 + wc * 16 + l15;
        vtv[nf] = vt[e];
        dcv[nf] = dec[bb * Dd + e];
    }

    // A chunk index = m0*32 + 2T + h  (linear in global tile counter T=0..31)
    const size_t abase = (size_t)m0 * 32 * 8192;
    const size_t bbase = (size_t)et * 32 * 8192;
    const int uoff = tid * 8;                    // per-thread 16B within chunk

    auto stA = [&](int T, int h) {
        const _Float16* gp = A_p + abase + ((size_t)(2 * T + h) << 13) + uoff;
        _Float16* lp = lds + ((((T & 1) * 2 + h) << 13) + (wid << 9));
        __builtin_amdgcn_global_load_lds((const GLOBAL_AS void*)gp,
                                         (LDS_AS void*)lp, 16, 0, 0);
        __builtin_amdgcn_global_load_lds((const GLOBAL_AS void*)(gp + 4096),
                                         (LDS_AS void*)(lp + 4096), 16, 0, 0);
    };
    auto stB = [&](int T, int h) {
        const _Float16* gp = W1TT + bbase + ((size_t)((T & 15) * 2 + h) << 13) + uoff;
        _Float16* lp = lds + (32768 + (((T & 1) * 2 + h) << 13) + (wid << 9));
        __builtin_amdgcn_global_load_lds((const GLOBAL_AS void*)gp,
                                         (LDS_AS void*)lp, 16, 0, 0);
        __builtin_amdgcn_global_load_lds((const GLOBAL_AS void*)(gp + 4096),
                                         (LDS_AS void*)(lp + 4096), 16, 0, 0);
    };

    // LDS slot bases (halfword units). Even tiles -> slot 0, odd -> slot 1.
    // A: E.h0=0  E.h1=8192  O.h0=16384  O.h1=24576 ; B: +32768.

    // prologue: 9 half-chunks; VM(8) retires the first 5 (covers the pre-loop
    // reads + p1/p2/p3 reads of iter 0). In-flight after: 4 hc = steady entry.
    stA(0, 0); stB(0, 0); stB(0, 1); stA(0, 1); stA(1, 0);
    stB(1, 0); stB(1, 1); stA(1, 1); stA(2, 0);
    VM(8);
    BAR;
    RD_A(a0, 0);                // A(0,0)
    RD_B(b0, 32768);            // B(0,0)

#pragma unroll 1
    for (int i = 0; i < 16; ++i) {
        const int E = 2 * i, O = E + 1;
        const bool s1 = (i < 15), s2 = (i < 14);

        // ---- p1: q(A0,B0) of E ------------------------------------------
        RD_B(b1, 32768 + 8192);          // B(E,1)          (for p2)
        if (s1) stB(E + 2, 0);            // slot0-B-h0 freed at prev-p8
        BAR; LGKM(4);
        MFMAQ(a0, b0, 0, 0);
        BAR;

        // ---- p2: q(A0,B1) of E ------------------------------------------
        RD_A(a1, 8192);                  // A(E,1)          (for p3)
        if (s1) stB(E + 2, 1);            // slot0-B-h1 freed at p1
        BAR; LGKM(8);
        MFMAQ(a0, b1, 0, 2);
        BAR;

        // ---- p3: q(A1,B1) of E ------------------------------------------
        RD_A(a0, 16384);                 // A(O,0)          (for p5)
        if (s1) stA(E + 2, 1);            // slot0-A-h1 freed at p2
        BAR; LGKM(8);
        MFMAQ(a1, b1, 4, 2);
        BAR;

        // ---- p4: q(A1,B0) of E ------------------------------------------
        if (s1) stA(O + 2, 0);            // slot1-A-h0 freed at p3
        if (s1) { VM(8); } else { VM(0); }  // retire prev p5-p8 stages
        BAR;
        MFMAQ(a1, b0, 4, 0);
        RD_B(b0, 32768 + 16384);         // B(O,0) (post-MFMA, for p5)
        BAR;

        // ---- p5: q(A0,B0) of O ------------------------------------------
        RD_B(b1, 32768 + 16384 + 8192);  // B(O,1)          (for p6)
        if (s1) stB(O + 2, 0);            // slot1-B-h0 freed at p4
        BAR; LGKM(4);
        MFMAQ(a0, b0, 0, 0);
        BAR;

        // ---- p6: q(A0,B1) of O ------------------------------------------
        RD_A(a1, 16384 + 8192);          // A(O,1)          (for p7)
        if (s1) stB(O + 2, 1);            // slot1-B-h1 freed at p5
        BAR; LGKM(8);
        MFMAQ(a0, b1, 0, 2);
        BAR;

        // ---- p7: q(A1,B1) of O ------------------------------------------
        if (s1) RD_A(a0, 0);             // A(E+2,0)        (for next p1)
        if (s1) stA(O + 2, 1);            // slot1-A-h1 freed at p6
        BAR;
        if (s1) { LGKM(8); } else { LGKM(0); }
        MFMAQ(a1, b1, 4, 2);
        BAR;

        // ---- p8: q(A1,B0) of O ------------------------------------------
        if (s2) stA(E + 4, 0);            // slot0-A-h0 freed at p7
        if (s2)      { VM(8); }           // retire this iter's p1-p4 stages
        else if (s1) { VM(6); }           // i=14: p8 stage skipped
        else         { VM(0); }           // i=15: drain
        BAR;
        MFMAQ(a1, b0, 4, 0);
        if (s1) RD_B(b0, 32768);         // B(E+2,0) (post-MFMA, next p1)
        BAR;

        // ---- per-mtile epilogue (LDS-free; pipeline keeps flowing) -------
        if ((i & 7) == 7) {
            const int mt = m0 + (i >> 3);
#pragma unroll
            for (int hm = 0; hm < 8; ++hm) {
                const int h = hm >> 2, mq = hm & 3;
#pragma unroll
                for (int r = 0; r < 4; ++r) {
                    float s = 0.f;
#pragma unroll
                    for (int nf = 0; nf < 4; ++nf) {
                        float x  = acc[hm][nf][r] + dcv[nf];
                        float ex = __expf(2.f * x);
                        s += (1.f - 2.f * __builtin_amdgcn_rcpf(ex + 1.f)) * vtv[nf];
                    }
#pragma unroll
                    for (int off = 1; off < 16; off <<= 1)
                        s += __shfl_xor(s, off, 16);
                    if (l15 == 0)
                        u_part[(size_t)(et * 4 + wc) * M + (size_t)mt * 256
                               + h * 128 + mq * 32 + wr * 16 + qq * 4 + r] = s;
                }
            }
#pragma unroll
            for (int hm = 0; hm < 8; ++hm)
#pragma unroll
                for (int nf = 0; nf < 4; ++nf)
                    acc[hm][nf] = (f32x4){0.f, 0.f, 0.f, 0.f};
        }
    }
}

// ---------------------------------------------------------------------------
// Kernel 4: masked log-softmax over N=2048 per batch row (16 partial slices).
// ---------------------------------------------------------------------------
__global__ void softmax_k(const float* __restrict__ up, const int* __restrict__ mask,
                          float* __restrict__ out) {
    __shared__ float red[8];
    int b = blockIdx.x, tid = threadIdx.x;
    float l[8];
#pragma unroll
    for (int i = 0; i < 8; ++i) {
        int n = i * 256 + tid;
        float s = up[(size_t)b * Nn + n];
#pragma unroll
        for (int et = 1; et < 16; ++et) s += up[(size_t)et * M + (size_t)b * Nn + n];
        l[i] = s + (mask[b * Nn + n] ? 0.f : -103.278931f);  // ln(2^-149)
    }
    float m = l[0];
#pragma unroll
    for (int i = 1; i < 8; ++i) m = fmaxf(m, l[i]);
#pragma unroll
    for (int o = 32; o >= 1; o >>= 1) m = fmaxf(m, __shfl_xor(m, o, 64));
    if ((tid & 63) == 0) red[tid >> 6] = m;
    __syncthreads();
    m = fmaxf(fmaxf(red[0], red[1]), fmaxf(red[2], red[3]));
    float s = 0.f;
#pragma unroll
    for (int i = 0; i < 8; ++i) s += expf(l[i] - m);
#pragma unroll
    for (int o = 32; o >= 1; o >>= 1) s += __shfl_xor(s, o, 64);
    if ((tid & 63) == 0) red[4 + (tid >> 6)] = s;
    __syncthreads();
    float lse = m + logf(red[4] + red[5] + red[6] + red[7]);
#pragma unroll
    for (int i = 0; i < 8; ++i)
        out[(size_t)b * Nn + i * 256 + tid] = l[i] - lse;
}

// ---------------------------------------------------------------------------
extern "C" void kernel_launch(void* const* d_in, const int* in_sizes, int n_in,
                              void* d_out, int out_size, void* d_ws, size_t ws_size,
                              hipStream_t stream) {
    const float* encoded = (const float*)d_in[0];
    const float* dstate  = (const float*)d_in[1];
    const int*   mask    = (const int*)d_in[2];
    const float* W1      = (const float*)d_in[3];
    const float* W2      = (const float*)d_in[4];
    const float* vt      = (const float*)d_in[5];
    float* out = (float*)d_out;

    // ws layout: u_part (4 MiB) | dec (128 KB) | W1TT (2 MiB) | A_p (128 MiB)
    char* ws = (char*)d_ws;
    float*    u_part = (float*)ws;
    float*    dec    = (float*)(ws + (size_t)16 * M * 4);
    _Float16* W1TT   = (_Float16*)(ws + (size_t)16 * M * 4 + (size_t)Bb * Dd * 4);
    _Float16* A_p    = (_Float16*)(ws + (size_t)16 * M * 4 + (size_t)Bb * Dd * 4
                                   + (size_t)Dd * Dd * 2);

    static bool attr_done = false;
    if (!attr_done) {
        hipFuncSetAttribute(reinterpret_cast<const void*>(gemm8),
                            hipFuncAttributeMaxDynamicSharedMemorySize, 131072);
        attr_done = true;
    }

    prep_w1<<<512, 256, 0, stream>>>(W1, W1TT);
    dec_kernel<<<dim3(32, 16), 256, 0, stream>>>(dstate, W2, dec);
    prep_enc<<<8192, 256, 0, stream>>>(encoded, A_p);
    gemm8<<<512, 512, 131072, stream>>>(A_p, W1TT, dec, vt, u_part);
    softmax_k<<<32, 256, 0, stream>>>(u_part, mask, out);
}

// Round 4
// 565.646 us; speedup vs baseline: 1.1724x; 1.1724x over previous
//
#include <hip/hip_runtime.h>

typedef _Float16 half8 __attribute__((ext_vector_type(8)));
typedef __fp16   pk2   __attribute__((ext_vector_type(2)));
typedef float    f32x4 __attribute__((ext_vector_type(4)));

#define GLOBAL_AS __attribute__((address_space(1)))
#define LDS_AS    __attribute__((address_space(3)))

static constexpr int Bb = 32;
static constexpr int Nn = 2048;
static constexpr int Dd = 1024;
static constexpr int M  = Bb * Nn;   // 65536 rows of the big GEMM

// ---------------------------------------------------------------------------
// Packed operand layout (shared by prep kernels and gemm8):
// chunk = one (tile, half) = 128 rows/cols x 64 k of f16 = 16 KB, staged
// linearly by global_load_lds. Within a chunk, half8 unit u = q*128 + s
// (q = k-octet 0..7) holds logical row  r = s ^ (2*(q&3))  -- the XOR is the
// LDS bank swizzle, pre-baked into the GLOBAL layout (linear LDS dest +
// inverse-swizzled source + swizzled ds_read, per the both-sides rule).
// A_p chunks: [mtile(256)][t(16)][h(2)]   W1TT chunks: [et(4)][t(16)][h(2)]
// ---------------------------------------------------------------------------

// Kernel 1a: pack W1 (f32 [d][e]) -> swizzled f16 chunks.
__global__ void prep_w1(const float* __restrict__ W1, _Float16* __restrict__ W1TT) {
    int g = blockIdx.x * 256 + threadIdx.x;   // 131072 half8 units
    int chunk = g >> 10;                      // et*32 + t*2 + h
    int u = g & 1023;
    int q = u >> 7, sc = u & 127;
    int cl = sc ^ (2 * (q & 3));
    int et = chunk >> 5, t = (chunk >> 1) & 15, h = chunk & 1;
    int e  = et * 256 + h * 128 + cl;
    int k0 = t * 64 + q * 8;
    half8 hh;
#pragma unroll
    for (int j = 0; j < 8; ++j)
        hh[j] = (_Float16)W1[(size_t)(k0 + j) * Dd + e];
    *(half8*)(W1TT + (size_t)g * 8) = hh;
}

// Kernel 1b: convert+pack encoded (f32 [m][d]) -> swizzled f16 chunks.
// LDS-staged transpose keeps both the 256 MiB read and 128 MiB write coalesced.
__global__ void prep_enc(const float* __restrict__ A, _Float16* __restrict__ A_p) {
    __shared__ _Float16 T[128 * 64];          // 16 KB, slot-XOR banked
    const int c = blockIdx.x;                 // 8192 chunks
    const int tid = threadIdx.x;
    const int mtile = c >> 5, t = (c >> 1) & 15, h = c & 1;
    const int r = tid >> 1, kh = tid & 1;     // thread reads 128B of one row
    const float* src = A + (size_t)(mtile * 256 + h * 128 + r) * Dd + t * 64 + kh * 32;
    const int rx = r & 7;
#pragma unroll
    for (int i = 0; i < 4; ++i) {
        f32x4 a  = *(const f32x4*)(src + i * 8);
        f32x4 b2 = *(const f32x4*)(src + i * 8 + 4);
        half8 hh; pk2 p;
        p = __builtin_amdgcn_cvt_pkrtz(a.x, a.y);   hh[0] = p[0]; hh[1] = p[1];
        p = __builtin_amdgcn_cvt_pkrtz(a.z, a.w);   hh[2] = p[0]; hh[3] = p[1];
        p = __builtin_amdgcn_cvt_pkrtz(b2.x, b2.y); hh[4] = p[0]; hh[5] = p[1];
        p = __builtin_amdgcn_cvt_pkrtz(b2.z, b2.w); hh[6] = p[0]; hh[7] = p[1];
        *(half8*)(T + r * 64 + (((kh * 4 + i) ^ rx) * 8)) = hh;   // slot ^= r&7
    }
    __syncthreads();
    const size_t cb = (size_t)c * 8192;
#pragma unroll
    for (int i = 0; i < 4; ++i) {
        int u = i * 256 + tid;
        int q = u >> 7, sr = u & 127;
        int lr = sr ^ (2 * (q & 3));
        half8 hh = *(const half8*)(T + lr * 64 + ((q ^ (lr & 7)) * 8));
        *(half8*)(A_p + cb + (size_t)u * 8) = hh;  // fully coalesced 16B stores
    }
}

// ---------------------------------------------------------------------------
// Kernel 2: dec[b][e] = decoder_state[b] @ W2   (32x1024)
// ---------------------------------------------------------------------------
__global__ void dec_kernel(const float* __restrict__ ds, const float* __restrict__ W2,
                           float* __restrict__ dec) {
    __shared__ float part[4][64];
    int b = blockIdx.x, ech = blockIdx.y;
    int tid = threadIdx.x;
    int e = ech * 64 + (tid & 63);
    int dc = tid >> 6;
    float acc = 0.f;
#pragma unroll 4
    for (int d = dc * 256; d < dc * 256 + 256; ++d)
        acc += ds[b * Dd + d] * W2[(size_t)d * Dd + e];
    part[dc][tid & 63] = acc;
    __syncthreads();
    if (tid < 64)
        dec[b * Dd + e] = part[0][tid] + part[1][tid] + part[2][tid] + part[3][tid];
}

// ---------------------------------------------------------------------------
// Kernel 3: 256x256 tile, 8 waves, 4 FAT phases per 2-K-tile iteration
// (32 MFMA per phase -> halves barrier/drain overhead per MFMA vs 8-phase).
// Phase = { in-phase ds_reads (16 or 8 b128); stage (3 or 1 half-chunks);
//           BAR; lgkmcnt(0); setprio(1); 32 MFMA; setprio(0); VM(gate); BAR }
// VM gate protects the NEXT phase's reads (placed before the barrier so every
// wave's loads retire before any wave reads them -- cross-wave visibility).
// Steady gates: end-p1 VM(6), end-p2 VM(2), end-p3 VM(6), end-p4 VM(2);
// ledger-verified; never vmcnt(0) mid-loop (single VM(0) at i=7 p3).
// Fragments: a[4][2] + b0[2][2] + b1[2][2] = 64 VGPR (+128 acc) -> no spill.
// ---------------------------------------------------------------------------
#define BAR     asm volatile("s_barrier" ::: "memory")
#define LGKM(n) asm volatile("s_waitcnt lgkmcnt(" #n ")" ::: "memory")
#define VM(n)   asm volatile("s_waitcnt vmcnt(" #n ")" ::: "memory")
#define PRIO1   __builtin_amdgcn_s_setprio(1)
#define PRIO0   __builtin_amdgcn_s_setprio(0)

#define RD_A(dst, base) do { _Pragma("unroll") \
  for (int ks = 0; ks < 2; ++ks) { const int qb = ((ks * 4 + qq) * 128) * 8; \
    _Pragma("unroll") for (int m2 = 0; m2 < 4; ++m2) \
      dst[m2][ks] = *(const half8*)&lds[(base) + qb + (m2 * 32 + rA) * 8]; } } while (0)

#define RD_B(dst, base) do { _Pragma("unroll") \
  for (int ks = 0; ks < 2; ++ks) { const int qb = ((ks * 4 + qq) * 128) * 8; \
    _Pragma("unroll") for (int j2 = 0; j2 < 2; ++j2) \
      dst[j2][ks] = *(const half8*)&lds[(base) + qb + (j2 * 64 + rB) * 8]; } } while (0)

#define MFMAQ(A_, B_, ro, co) do { \
  _Pragma("unroll") for (int m2 = 0; m2 < 4; ++m2) \
  _Pragma("unroll") for (int j2 = 0; j2 < 2; ++j2) { \
    acc[(ro) + m2][(co) + j2] = __builtin_amdgcn_mfma_f32_16x16x32_f16( \
        A_[m2][0], B_[j2][0], acc[(ro) + m2][(co) + j2], 0, 0, 0); \
    acc[(ro) + m2][(co) + j2] = __builtin_amdgcn_mfma_f32_16x16x32_f16( \
        A_[m2][1], B_[j2][1], acc[(ro) + m2][(co) + j2], 0, 0, 0); } } while (0)

__global__ __launch_bounds__(512) void gemm8(
    const _Float16* __restrict__ A_p, const _Float16* __restrict__ W1TT,
    const float* __restrict__ dec, const float* __restrict__ vt,
    float* __restrict__ u_part)          // [4][65536]
{
    extern __shared__ _Float16 lds[];    // 65536 halfs = 128 KB

    const int g  = blockIdx.x;                   // 0..1023
    const int wg = (g & 7) * 128 + (g >> 3);     // XCD-chunked swizzle (1024%8==0)
    const int et    = wg & 3;                    // 4 consecutive wg share mtile
    const int mtile = wg >> 2;

    const int tid  = threadIdx.x;
    const int lane = tid & 63, wid = tid >> 6;
    const int wr = wid >> 2, wc = wid & 3;
    const int qq = lane >> 4, l15 = lane & 15;
    const int l15s = l15 ^ (2 * qq);             // read-side bank swizzle
    const int rA = wr * 16 + l15s;
    const int rB = wc * 16 + l15s;

    f32x4 acc[8][4] = {};
    half8 a[4][2], b0[2][2], b1[2][2];

    const size_t abase = (size_t)mtile * 32 * 8192;
    const size_t bbase = (size_t)et * 32 * 8192;
    const int uoff = tid * 8;                    // per-thread 16B within chunk

    auto stA = [&](int T, int h) {
        const _Float16* gp = A_p + abase + ((size_t)(T * 2 + h) << 13) + uoff;
        _Float16* lp = lds + ((((T & 1) * 2 + h) << 13) + (wid << 9));
        __builtin_amdgcn_global_load_lds((const GLOBAL_AS void*)gp,
                                         (LDS_AS void*)lp, 16, 0, 0);
        __builtin_amdgcn_global_load_lds((const GLOBAL_AS void*)(gp + 4096),
                                         (LDS_AS void*)(lp + 4096), 16, 0, 0);
    };
    auto stB = [&](int T, int h) {
        const _Float16* gp = W1TT + bbase + ((size_t)(T * 2 + h) << 13) + uoff;
        _Float16* lp = lds + (32768 + (((T & 1) * 2 + h) << 13) + (wid << 9));
        __builtin_amdgcn_global_load_lds((const GLOBAL_AS void*)gp,
                                         (LDS_AS void*)lp, 16, 0, 0);
        __builtin_amdgcn_global_load_lds((const GLOBAL_AS void*)(gp + 4096),
                                         (LDS_AS void*)(lp + 4096), 16, 0, 0);
    };

    // LDS bases (halfword units): tile slot = T&1.
    // A: slot0 h0=0, h1=8192 ; slot1 h0=16384, h1=24576.  B: +32768 each.

    // prologue: tile0 fully staged (4 hc = 8 loads); VM(2) retires the 6 loads
    // p1 reads (A00,B00,B01); A01 stays in flight for p2.
    stA(0, 0); stB(0, 0); stB(0, 1); stA(0, 1);
    VM(2);
    BAR;

#pragma unroll 1
    for (int i = 0; i < 8; ++i) {
        const int E = 2 * i, O = E + 1;
        const bool s = (i < 7);

        // ---- p1: acc[0-3] x tile E  (reads A(E,0), B(E,0), B(E,1)) -------
        RD_A(a, 0);
        RD_B(b0, 32768);
        RD_B(b1, 40960);
        stA(O, 0); stB(O, 0); stB(O, 1);        // slot1 <- tile O (read p3)
        BAR; LGKM(0);
        PRIO1; MFMAQ(a, b0, 0, 0); MFMAQ(a, b1, 0, 2); PRIO0;
        VM(6);                                   // retire A(E,1) for p2
        BAR;

        // ---- p2: acc[4-7] x tile E  (reads A(E,1)) -----------------------
        RD_A(a, 8192);
        stA(O, 1);                               // slot1 A-h1 (read p4)
        BAR; LGKM(0);
        PRIO1; MFMAQ(a, b0, 4, 0); MFMAQ(a, b1, 4, 2); PRIO0;
        VM(2);                                   // retire tile-O 3hc for p3
        BAR;

        // ---- p3: acc[0-3] x tile O  (reads A(O,0), B(O,0), B(O,1)) -------
        RD_A(a, 16384);
        RD_B(b0, 49152);
        RD_B(b1, 57344);
        if (s) { stA(E + 2, 0); stB(E + 2, 0); stB(E + 2, 1); }  // slot0 <- E+2
        BAR; LGKM(0);
        PRIO1; MFMAQ(a, b0, 0, 0); MFMAQ(a, b1, 0, 2); PRIO0;
        if (s) { VM(6); } else { VM(0); }        // retire A(O,1) for p4
        BAR;

        // ---- p4: acc[4-7] x tile O  (reads A(O,1)) -----------------------
        RD_A(a, 24576);
        if (s) stA(E + 2, 1);                    // slot0 A-h1
        BAR; LGKM(0);
        PRIO1; MFMAQ(a, b0, 4, 0); MFMAQ(a, b1, 4, 2); PRIO0;
        VM(2);                                   // retire tile-(E+2) 3hc for p1'
        BAR;
    }

    // ---- epilogue: tanh(c + dec) * vt, reduce over this block's 256 cols ----
    const int b = mtile >> 3;                    // 8 mtiles per batch row
    float vtv[4], dcv[4];
#pragma unroll
    for (int nf = 0; nf < 4; ++nf) {
        int e = et * 256 + (nf >> 1) * 128 + (nf & 1) * 64 + wc * 16 + l15;
        vtv[nf] = vt[e];
        dcv[nf] = dec[b * Dd + e];
    }
    float* usum = (float*)lds;   // [4 wc][256 rows]; all staging drained
#pragma unroll
    for (int hm = 0; hm < 8; ++hm) {
        const int h = hm >> 2, mq = hm & 3;
#pragma unroll
        for (int r = 0; r < 4; ++r) {
            float sv = 0.f;
#pragma unroll
            for (int nf = 0; nf < 4; ++nf) {
                float x  = acc[hm][nf][r] + dcv[nf];
                float ex = __expf(2.f * x);
                sv += (1.f - 2.f * __builtin_amdgcn_rcpf(ex + 1.f)) * vtv[nf];
            }
#pragma unroll
            for (int off = 1; off < 16; off <<= 1) sv += __shfl_xor(sv, off, 16);
            if (l15 == 0)
                usum[wc * 256 + h * 128 + mq * 32 + wr * 16 + qq * 4 + r] = sv;
        }
    }
    __syncthreads();
    if (tid < 256) {
        float v = usum[tid] + usum[256 + tid] + usum[512 + tid] + usum[768 + tid];
        u_part[(size_t)et * M + (size_t)mtile * 256 + tid] = v;
    }
}

// ---------------------------------------------------------------------------
// Kernel 4: masked log-softmax over N=2048 per batch row (4 partial slices).
// ---------------------------------------------------------------------------
__global__ void softmax_k(const float* __restrict__ up, const int* __restrict__ mask,
                          float* __restrict__ out) {
    __shared__ float red[8];
    int b = blockIdx.x, tid = threadIdx.x;
    float l[8];
#pragma unroll
    for (int i = 0; i < 8; ++i) {
        int n = i * 256 + tid;
        float s = up[(size_t)b * Nn + n];
#pragma unroll
        for (int et = 1; et < 4; ++et) s += up[(size_t)et * M + (size_t)b * Nn + n];
        l[i] = s + (mask[b * Nn + n] ? 0.f : -103.278931f);  // ln(2^-149)
    }
    float m = l[0];
#pragma unroll
    for (int i = 1; i < 8; ++i) m = fmaxf(m, l[i]);
#pragma unroll
    for (int o = 32; o >= 1; o >>= 1) m = fmaxf(m, __shfl_xor(m, o, 64));
    if ((tid & 63) == 0) red[tid >> 6] = m;
    __syncthreads();
    m = fmaxf(fmaxf(red[0], red[1]), fmaxf(red[2], red[3]));
    float s = 0.f;
#pragma unroll
    for (int i = 0; i < 8; ++i) s += expf(l[i] - m);
#pragma unroll
    for (int o = 32; o >= 1; o >>= 1) s += __shfl_xor(s, o, 64);
    if ((tid & 63) == 0) red[4 + (tid >> 6)] = s;
    __syncthreads();
    float lse = m + logf(red[4] + red[5] + red[6] + red[7]);
#pragma unroll
    for (int i = 0; i < 8; ++i)
        out[(size_t)b * Nn + i * 256 + tid] = l[i] - lse;
}

// ---------------------------------------------------------------------------
extern "C" void kernel_launch(void* const* d_in, const int* in_sizes, int n_in,
                              void* d_out, int out_size, void* d_ws, size_t ws_size,
                              hipStream_t stream) {
    const float* encoded = (const float*)d_in[0];
    const float* dstate  = (const float*)d_in[1];
    const int*   mask    = (const int*)d_in[2];
    const float* W1      = (const float*)d_in[3];
    const float* W2      = (const float*)d_in[4];
    const float* vt      = (const float*)d_in[5];
    float* out = (float*)d_out;

    // ws layout: u_part (1 MiB) | dec (128 KB) | W1TT (2 MiB) | A_p (128 MiB)
    char* ws = (char*)d_ws;
    float*    u_part = (float*)ws;
    float*    dec    = (float*)(ws + (size_t)4 * M * 4);
    _Float16* W1TT   = (_Float16*)(ws + (size_t)4 * M * 4 + (size_t)Bb * Dd * 4);
    _Float16* A_p    = (_Float16*)(ws + (size_t)4 * M * 4 + (size_t)Bb * Dd * 4
                                   + (size_t)Dd * Dd * 2);

    static bool attr_done = false;
    if (!attr_done) {
        hipFuncSetAttribute(reinterpret_cast<const void*>(gemm8),
                            hipFuncAttributeMaxDynamicSharedMemorySize, 131072);
        attr_done = true;
    }

    prep_w1<<<512, 256, 0, stream>>>(W1, W1TT);
    dec_kernel<<<dim3(32, 16), 256, 0, stream>>>(dstate, W2, dec);
    prep_enc<<<8192, 256, 0, stream>>>(encoded, A_p);
    gemm8<<<1024, 512, 131072, stream>>>(A_p, W1TT, dec, vt, u_part);
    softmax_k<<<32, 256, 0, stream>>>(u_part, mask, out);
}

// Round 5
// 554.524 us; speedup vs baseline: 1.1959x; 1.0201x over previous
//
#include <hip/hip_runtime.h>

typedef _Float16 half8 __attribute__((ext_vector_type(8)));
typedef _Float16 half4 __attribute__((ext_vector_type(4)));
typedef __fp16   pk2   __attribute__((ext_vector_type(2)));
typedef float    f32x4 __attribute__((ext_vector_type(4)));

#define GLOBAL_AS __attribute__((address_space(1)))
#define LDS_AS    __attribute__((address_space(3)))

static constexpr int Bb = 32;
static constexpr int Nn = 2048;
static constexpr int Dd = 1024;
static constexpr int M  = Bb * Nn;   // 65536 rows of the big GEMM

// ---------------------------------------------------------------------------
// Packed operand layout (shared by prep kernels and gemm8):
// chunk = one (tile, half) = 128 rows/cols x 64 k of f16 = 16 KB, staged
// linearly by global_load_lds. Within a chunk, half8 unit u = q*128 + s
// (q = k-octet 0..7) holds logical row  r = s ^ (2*(q&3))  -- the XOR is the
// LDS bank swizzle, pre-baked into the GLOBAL layout (linear LDS dest +
// inverse-swizzled source + swizzled ds_read, per the both-sides rule).
// A_p chunks: [mtile(256)][t(16)][h(2)]   W1TT chunks: [et(4)][t(16)][h(2)]
// ---------------------------------------------------------------------------

// Kernel 1a: pack W1 (f32 [d][e]) -> swizzled f16 chunks.
__global__ void prep_w1(const float* __restrict__ W1, _Float16* __restrict__ W1TT) {
    int g = blockIdx.x * 256 + threadIdx.x;   // 131072 half8 units
    int chunk = g >> 10;                      // et*32 + t*2 + h
    int u = g & 1023;
    int q = u >> 7, sc = u & 127;
    int cl = sc ^ (2 * (q & 3));
    int et = chunk >> 5, t = (chunk >> 1) & 15, h = chunk & 1;
    int e  = et * 256 + h * 128 + cl;
    int k0 = t * 64 + q * 8;
    half8 hh;
#pragma unroll
    for (int j = 0; j < 8; ++j)
        hh[j] = (_Float16)W1[(size_t)(k0 + j) * Dd + e];
    *(half8*)(W1TT + (size_t)g * 8) = hh;
}

// Kernel 1b: convert+pack encoded (f32 [m][d]) -> swizzled f16 chunks.
// Coalesced read phase: lanes 0-15 sweep ONE row contiguously (4 rows x 256 B
// per instruction = 16 sectors, vs 64 sectors in the old 2-lanes-per-row map).
// LDS transpose stage unchanged; output stores fully coalesced.
__global__ void prep_enc(const float* __restrict__ A, _Float16* __restrict__ A_p) {
    __shared__ _Float16 T[128 * 64];          // 16 KB, slot-XOR banked
    const int c = blockIdx.x;                 // 8192 chunks
    const int tid = threadIdx.x;
    const int mtile = c >> 5, t = (c >> 1) & 15, h = c & 1;
    const int r0 = tid >> 4, ks = tid & 15;   // pass covers 16 rows x 64 floats
    const int q = ks >> 1, h4 = ks & 1;       // unit q, low/high half4
    const float* src0 = A + (size_t)(mtile * 256 + h * 128 + r0) * Dd
                          + t * 64 + ks * 4;
#pragma unroll
    for (int p = 0; p < 8; ++p) {
        const int r = p * 16 + r0;
        f32x4 a = *(const f32x4*)(src0 + (size_t)p * 16 * Dd);
        pk2 p0 = __builtin_amdgcn_cvt_pkrtz(a.x, a.y);
        pk2 p1 = __builtin_amdgcn_cvt_pkrtz(a.z, a.w);
        half4 hh; hh[0] = p0[0]; hh[1] = p0[1]; hh[2] = p1[0]; hh[3] = p1[1];
        *(half4*)(T + r * 64 + ((q ^ (r & 7)) * 8) + h4 * 4) = hh;
    }
    __syncthreads();
    const size_t cb = (size_t)c * 8192;
#pragma unroll
    for (int i = 0; i < 4; ++i) {
        int u = i * 256 + tid;
        int qq2 = u >> 7, sr = u & 127;
        int lr = sr ^ (2 * (qq2 & 3));
        half8 hh = *(const half8*)(T + lr * 64 + ((qq2 ^ (lr & 7)) * 8));
        *(half8*)(A_p + cb + (size_t)u * 8) = hh;  // fully coalesced 16B stores
    }
}

// ---------------------------------------------------------------------------
// Kernel 2: dec[b][e] = decoder_state[b] @ W2   (32x1024)
// ---------------------------------------------------------------------------
__global__ void dec_kernel(const float* __restrict__ ds, const float* __restrict__ W2,
                           float* __restrict__ dec) {
    __shared__ float part[4][64];
    int b = blockIdx.x, ech = blockIdx.y;
    int tid = threadIdx.x;
    int e = ech * 64 + (tid & 63);
    int dc = tid >> 6;
    float acc = 0.f;
#pragma unroll 4
    for (int d = dc * 256; d < dc * 256 + 256; ++d)
        acc += ds[b * Dd + d] * W2[(size_t)d * Dd + e];
    part[dc][tid & 63] = acc;
    __syncthreads();
    if (tid < 64)
        dec[b * Dd + e] = part[0][tid] + part[1][tid] + part[2][tid] + part[3][tid];
}

// ---------------------------------------------------------------------------
// Kernel 3: 256x256 tile, 8 waves, ONE barrier per K-tile with intra-tile
// read/MFMA overlap via counted lgkmcnt. Per tile: issue 4 staging gloads
// (tile T+1 -> other slot) + all 24 ds_read_b128 up front, then gate each
// MFMA quadrant on only its own operands: LGKM(12) {ax+b0}, LGKM(8) {b1},
// LGKM(0) {ay}. The tail 12 reads drain UNDER the first 32 MFMA instead of
// serializing (the r4 fat-phase structure alternated CU-wide LDS bursts and
// MFMA bursts -> 36% util ceiling). VM(0)+BAR once per tile retires staging
// issued at tile start (~2300 cyc slack, HBM latency covered).
// Fragments: ax/ay[4][2] + b0/b1[2][2] = 96 VGPR + 128 acc ~= 224 (no spill).
// ---------------------------------------------------------------------------
#define BAR     asm volatile("s_barrier" ::: "memory")
#define LGKM(n) asm volatile("s_waitcnt lgkmcnt(" #n ")" ::: "memory")
#define VM(n)   asm volatile("s_waitcnt vmcnt(" #n ")" ::: "memory")
#define PRIO1   __builtin_amdgcn_s_setprio(1)
#define PRIO0   __builtin_amdgcn_s_setprio(0)

#define RD_A(dst, base) do { _Pragma("unroll") \
  for (int ks = 0; ks < 2; ++ks) { const int qb = ((ks * 4 + qq) * 128) * 8; \
    _Pragma("unroll") for (int m2 = 0; m2 < 4; ++m2) \
      dst[m2][ks] = *(const half8*)&lds[(base) + qb + (m2 * 32 + rA) * 8]; } } while (0)

#define RD_B(dst, base) do { _Pragma("unroll") \
  for (int ks = 0; ks < 2; ++ks) { const int qb = ((ks * 4 + qq) * 128) * 8; \
    _Pragma("unroll") for (int j2 = 0; j2 < 2; ++j2) \
      dst[j2][ks] = *(const half8*)&lds[(base) + qb + (j2 * 64 + rB) * 8]; } } while (0)

#define MFMAQ(A_, B_, ro, co) do { \
  _Pragma("unroll") for (int m2 = 0; m2 < 4; ++m2) \
  _Pragma("unroll") for (int j2 = 0; j2 < 2; ++j2) { \
    acc[(ro) + m2][(co) + j2] = __builtin_amdgcn_mfma_f32_16x16x32_f16( \
        A_[m2][0], B_[j2][0], acc[(ro) + m2][(co) + j2], 0, 0, 0); \
    acc[(ro) + m2][(co) + j2] = __builtin_amdgcn_mfma_f32_16x16x32_f16( \
        A_[m2][1], B_[j2][1], acc[(ro) + m2][(co) + j2], 0, 0, 0); } } while (0)

__global__ __launch_bounds__(512) void gemm8(
    const _Float16* __restrict__ A_p, const _Float16* __restrict__ W1TT,
    const float* __restrict__ dec, const float* __restrict__ vt,
    float* __restrict__ u_part)          // [4][65536]
{
    extern __shared__ _Float16 lds[];    // 65536 halfs = 128 KB

    const int g  = blockIdx.x;                   // 0..1023
    const int wg = (g & 7) * 128 + (g >> 3);     // XCD-chunked swizzle (1024%8==0)
    const int et    = wg & 3;                    // 4 consecutive wg share mtile
    const int mtile = wg >> 2;

    const int tid  = threadIdx.x;
    const int lane = tid & 63, wid = tid >> 6;
    const int wr = wid >> 2, wc = wid & 3;
    const int qq = lane >> 4, l15 = lane & 15;
    const int l15s = l15 ^ (2 * qq);             // read-side bank swizzle
    const int rA = wr * 16 + l15s;
    const int rB = wc * 16 + l15s;

    f32x4 acc[8][4] = {};
    half8 ax[4][2], ay[4][2], b0[2][2], b1[2][2];

    const size_t abase = (size_t)mtile * 32 * 8192;
    const size_t bbase = (size_t)et * 32 * 8192;
    const int uoff = tid * 8;                    // per-thread 16B within chunk

    auto stA = [&](int T, int h) {
        const _Float16* gp = A_p + abase + ((size_t)(T * 2 + h) << 13) + uoff;
        _Float16* lp = lds + ((((T & 1) * 2 + h) << 13) + (wid << 9));
        __builtin_amdgcn_global_load_lds((const GLOBAL_AS void*)gp,
                                         (LDS_AS void*)lp, 16, 0, 0);
        __builtin_amdgcn_global_load_lds((const GLOBAL_AS void*)(gp + 4096),
                                         (LDS_AS void*)(lp + 4096), 16, 0, 0);
    };
    auto stB = [&](int T, int h) {
        const _Float16* gp = W1TT + bbase + ((size_t)(T * 2 + h) << 13) + uoff;
        _Float16* lp = lds + (32768 + (((T & 1) * 2 + h) << 13) + (wid << 9));
        __builtin_amdgcn_global_load_lds((const GLOBAL_AS void*)gp,
                                         (LDS_AS void*)lp, 16, 0, 0);
        __builtin_amdgcn_global_load_lds((const GLOBAL_AS void*)(gp + 4096),
                                         (LDS_AS void*)(lp + 4096), 16, 0, 0);
    };

    // LDS bases (halfword units): tile slot = T&1.
    // A: slot0 h0=0, h1=8192 ; slot1 h0=16384, h1=24576.  B: +32768 each.

    // prologue: tile 0 fully staged, drained once (per-block cost ~1-2 us).
    stA(0, 0); stA(0, 1); stB(0, 0); stB(0, 1);
    VM(0);
    BAR;

#pragma unroll 2
    for (int T = 0; T < 16; ++T) {
        const int As  = (T & 1) << 14;           // A slot base (halfwords)
        const int Bs2 = 32768 + ((T & 1) << 14); // B slot base
        const bool s = (T < 15);

        // staging for tile T+1 first: maximizes in-flight slack before VM(0)
        if (s) { stA(T + 1, 0); stA(T + 1, 1); stB(T + 1, 0); stB(T + 1, 1); }

        // issue all 24 ds_read_b128 up front; gate quadrants by counted lgkm
        RD_A(ax, As);                // 8 reads
        RD_B(b0, Bs2);               // 4
        RD_B(b1, Bs2 + 8192);        // 4
        RD_A(ay, As + 8192);         // 8

        LGKM(12);                    // ax + b0 resident (b1, ay still draining)
        PRIO1; MFMAQ(ax, b0, 0, 0); PRIO0;
        LGKM(8);                     // b1 resident
        PRIO1; MFMAQ(ax, b1, 0, 2); PRIO0;
        LGKM(0);                     // ay resident
        PRIO1; MFMAQ(ay, b0, 4, 0); MFMAQ(ay, b1, 4, 2); PRIO0;

        VM(0);                       // tile T+1 staging landed (issued ~2300 cyc ago)
        BAR;                         // slot T&1 free; tile T+1 readable
    }

    // ---- epilogue: tanh(c + dec) * vt, reduce over this block's 256 cols ----
    const int b = mtile >> 3;                    // 8 mtiles per batch row
    float vtv[4], dcv[4];
#pragma unroll
    for (int nf = 0; nf < 4; ++nf) {
        int e = et * 256 + (nf >> 1) * 128 + (nf & 1) * 64 + wc * 16 + l15;
        vtv[nf] = vt[e];
        dcv[nf] = dec[b * Dd + e];
    }
    float* usum = (float*)lds;   // [4 wc][256 rows]; all staging drained
#pragma unroll
    for (int hm = 0; hm < 8; ++hm) {
        const int h = hm >> 2, mq = hm & 3;
#pragma unroll
        for (int r = 0; r < 4; ++r) {
            float sv = 0.f;
#pragma unroll
            for (int nf = 0; nf < 4; ++nf) {
                float x  = acc[hm][nf][r] + dcv[nf];
                float ex = __expf(2.f * x);
                sv += (1.f - 2.f * __builtin_amdgcn_rcpf(ex + 1.f)) * vtv[nf];
            }
#pragma unroll
            for (int off = 1; off < 16; off <<= 1) sv += __shfl_xor(sv, off, 16);
            if (l15 == 0)
                usum[wc * 256 + h * 128 + mq * 32 + wr * 16 + qq * 4 + r] = sv;
        }
    }
    __syncthreads();
    if (tid < 256) {
        float v = usum[tid] + usum[256 + tid] + usum[512 + tid] + usum[768 + tid];
        u_part[(size_t)et * M + (size_t)mtile * 256 + tid] = v;
    }
}

// ---------------------------------------------------------------------------
// Kernel 4: masked log-softmax over N=2048 per batch row (4 partial slices).
// ---------------------------------------------------------------------------
__global__ void softmax_k(const float* __restrict__ up, const int* __restrict__ mask,
                          float* __restrict__ out) {
    __shared__ float red[8];
    int b = blockIdx.x, tid = threadIdx.x;
    float l[8];
#pragma unroll
    for (int i = 0; i < 8; ++i) {
        int n = i * 256 + tid;
        float s = up[(size_t)b * Nn + n];
#pragma unroll
        for (int et = 1; et < 4; ++et) s += up[(size_t)et * M + (size_t)b * Nn + n];
        l[i] = s + (mask[b * Nn + n] ? 0.f : -103.278931f);  // ln(2^-149)
    }
    float m = l[0];
#pragma unroll
    for (int i = 1; i < 8; ++i) m = fmaxf(m, l[i]);
#pragma unroll
    for (int o = 32; o >= 1; o >>= 1) m = fmaxf(m, __shfl_xor(m, o, 64));
    if ((tid & 63) == 0) red[tid >> 6] = m;
    __syncthreads();
    m = fmaxf(fmaxf(red[0], red[1]), fmaxf(red[2], red[3]));
    float s = 0.f;
#pragma unroll
    for (int i = 0; i < 8; ++i) s += expf(l[i] - m);
#pragma unroll
    for (int o = 32; o >= 1; o >>= 1) s += __shfl_xor(s, o, 64);
    if ((tid & 63) == 0) red[4 + (tid >> 6)] = s;
    __syncthreads();
    float lse = m + logf(red[4] + red[5] + red[6] + red[7]);
#pragma unroll
    for (int i = 0; i < 8; ++i)
        out[(size_t)b * Nn + i * 256 + tid] = l[i] - lse;
}

// ---------------------------------------------------------------------------
extern "C" void kernel_launch(void* const* d_in, const int* in_sizes, int n_in,
                              void* d_out, int out_size, void* d_ws, size_t ws_size,
                              hipStream_t stream) {
    const float* encoded = (const float*)d_in[0];
    const float* dstate  = (const float*)d_in[1];
    const int*   mask    = (const int*)d_in[2];
    const float* W1      = (const float*)d_in[3];
    const float* W2      = (const float*)d_in[4];
    const float* vt      = (const float*)d_in[5];
    float* out = (float*)d_out;

    // ws layout: u_part (1 MiB) | dec (128 KB) | W1TT (2 MiB) | A_p (128 MiB)
    char* ws = (char*)d_ws;
    float*    u_part = (float*)ws;
    float*    dec    = (float*)(ws + (size_t)4 * M * 4);
    _Float16* W1TT   = (_Float16*)(ws + (size_t)4 * M * 4 + (size_t)Bb * Dd * 4);
    _Float16* A_p    = (_Float16*)(ws + (size_t)4 * M * 4 + (size_t)Bb * Dd * 4
                                   + (size_t)Dd * Dd * 2);

    static bool attr_done = false;
    if (!attr_done) {
        hipFuncSetAttribute(reinterpret_cast<const void*>(gemm8),
                            hipFuncAttributeMaxDynamicSharedMemorySize, 131072);
        attr_done = true;
    }

    prep_w1<<<512, 256, 0, stream>>>(W1, W1TT);
    dec_kernel<<<dim3(32, 16), 256, 0, stream>>>(dstate, W2, dec);
    prep_enc<<<8192, 256, 0, stream>>>(encoded, A_p);
    gemm8<<<1024, 512, 131072, stream>>>(A_p, W1TT, dec, vt, u_part);
    softmax_k<<<32, 256, 0, stream>>>(u_part, mask, out);
}

// Round 6
// 524.558 us; speedup vs baseline: 1.2642x; 1.0571x over previous
//
#include <hip/hip_runtime.h>

typedef _Float16 half8 __attribute__((ext_vector_type(8)));
typedef _Float16 half4 __attribute__((ext_vector_type(4)));
typedef __fp16   pk2   __attribute__((ext_vector_type(2)));
typedef float    f32x4 __attribute__((ext_vector_type(4)));

#define GLOBAL_AS __attribute__((address_space(1)))
#define LDS_AS    __attribute__((address_space(3)))

static constexpr int Bb = 32;
static constexpr int Nn = 2048;
static constexpr int Dd = 1024;
static constexpr int M  = Bb * Nn;   // 65536 rows of the big GEMM

// ---------------------------------------------------------------------------
// Packed B layout (prep_w1 -> gemm8): chunk = (tile, half) = 128 cols x 64 k
// of f16 = 16 KB, staged linearly by global_load_lds. Within a chunk, half8
// unit u = q*128 + s (q = k-octet 0..7) holds logical col  c = s ^ (2*(q&3))
// -- the XOR is the LDS bank swizzle, pre-baked into the GLOBAL layout
// (linear LDS dest + inverse-swizzled source + swizzled ds_read).
// W1TT chunks: [et(4)][t(16)][h(2)]
// A is NOT pre-packed anymore: gemm8 reads encoded f32 directly and builds
// the same swizzled image in LDS via reg-staging (load -> cvt_pkrtz ->
// ds_write_b64 at the swizzled address). This deletes the prep_enc pass
// (256 MB read + 128 MB write) from the pipeline.
// ---------------------------------------------------------------------------

// Kernel 1a: pack W1 (f32 [d][e]) -> swizzled f16 chunks.
__global__ void prep_w1(const float* __restrict__ W1, _Float16* __restrict__ W1TT) {
    int g = blockIdx.x * 256 + threadIdx.x;   // 131072 half8 units
    int chunk = g >> 10;                      // et*32 + t*2 + h
    int u = g & 1023;
    int q = u >> 7, sc = u & 127;
    int cl = sc ^ (2 * (q & 3));
    int et = chunk >> 5, t = (chunk >> 1) & 15, h = chunk & 1;
    int e  = et * 256 + h * 128 + cl;
    int k0 = t * 64 + q * 8;
    half8 hh;
#pragma unroll
    for (int j = 0; j < 8; ++j)
        hh[j] = (_Float16)W1[(size_t)(k0 + j) * Dd + e];
    *(half8*)(W1TT + (size_t)g * 8) = hh;
}

// ---------------------------------------------------------------------------
// Kernel 2: dec[b][e] = decoder_state[b] @ W2   (32x1024)
// ---------------------------------------------------------------------------
__global__ void dec_kernel(const float* __restrict__ ds, const float* __restrict__ W2,
                           float* __restrict__ dec) {
    __shared__ float part[4][64];
    int b = blockIdx.x, ech = blockIdx.y;
    int tid = threadIdx.x;
    int e = ech * 64 + (tid & 63);
    int dc = tid >> 6;
    float acc = 0.f;
#pragma unroll 4
    for (int d = dc * 256; d < dc * 256 + 256; ++d)
        acc += ds[b * Dd + d] * W2[(size_t)d * Dd + e];
    part[dc][tid & 63] = acc;
    __syncthreads();
    if (tid < 64)
        dec[b * Dd + e] = part[0][tid] + part[1][tid] + part[2][tid] + part[3][tid];
}

// ---------------------------------------------------------------------------
// Kernel 3: 256x256 tile, 8 waves, fused f32->f16 A-staging.
// Per K-tile: issue 8 global_load_dwordx4 (A f32 -> regs, fully coalesced:
// 4 rows x 256 B per instr) + 4 global_load_lds (B f16) for tile T+1; issue
// tile T's 16 ds_read_b128 (a-h0, b0, b1); counted-lgkm quadrant overlap:
//   LGKM(4) q1(a.b0) | LGKM(0) q2(a.b1) | reload a<-h1 | LGKM(0) q3 q4
// then VM(4) [A regs landed] -> cvt_pkrtz + 8 ds_write_b64 into the swizzled
// image -> VM(0) [B landed] -> LGKM(0) -> BAR. One barrier per K-tile; loads
// have a full tile-period (~2400 cyc) of slack -> HBM latency covered.
// VGPR: a 32 + b0/b1 32 + aSt 32 (+128 acc in AGPR) -> fits 128-VGPR cap.
// ---------------------------------------------------------------------------
#define BAR     asm volatile("s_barrier" ::: "memory")
#define LGKM(n) asm volatile("s_waitcnt lgkmcnt(" #n ")" ::: "memory")
#define VM(n)   asm volatile("s_waitcnt vmcnt(" #n ")" ::: "memory")
#define PRIO1   __builtin_amdgcn_s_setprio(1)
#define PRIO0   __builtin_amdgcn_s_setprio(0)

#define RD_A(dst, base) do { _Pragma("unroll") \
  for (int ks = 0; ks < 2; ++ks) { const int qb = ((ks * 4 + qq) * 128) * 8; \
    _Pragma("unroll") for (int m2 = 0; m2 < 4; ++m2) \
      dst[m2][ks] = *(const half8*)&lds[(base) + qb + (m2 * 32 + rA) * 8]; } } while (0)

#define RD_B(dst, base) do { _Pragma("unroll") \
  for (int ks = 0; ks < 2; ++ks) { const int qb = ((ks * 4 + qq) * 128) * 8; \
    _Pragma("unroll") for (int j2 = 0; j2 < 2; ++j2) \
      dst[j2][ks] = *(const half8*)&lds[(base) + qb + (j2 * 64 + rB) * 8]; } } while (0)

#define MFMAQ(A_, B_, ro, co) do { \
  _Pragma("unroll") for (int m2 = 0; m2 < 4; ++m2) \
  _Pragma("unroll") for (int j2 = 0; j2 < 2; ++j2) { \
    acc[(ro) + m2][(co) + j2] = __builtin_amdgcn_mfma_f32_16x16x32_f16( \
        A_[m2][0], B_[j2][0], acc[(ro) + m2][(co) + j2], 0, 0, 0); \
    acc[(ro) + m2][(co) + j2] = __builtin_amdgcn_mfma_f32_16x16x32_f16( \
        A_[m2][1], B_[j2][1], acc[(ro) + m2][(co) + j2], 0, 0, 0); } } while (0)

__global__ __launch_bounds__(512) void gemm8(
    const float* __restrict__ encA, const _Float16* __restrict__ W1TT,
    const float* __restrict__ dec, const float* __restrict__ vt,
    float* __restrict__ u_part)          // [4][65536]
{
    extern __shared__ _Float16 lds[];    // 65536 halfs = 128 KB

    const int g  = blockIdx.x;                   // 0..1023
    const int wg = (g & 7) * 128 + (g >> 3);     // XCD-chunked swizzle (1024%8==0)
    const int et    = wg & 3;                    // 4 consecutive wg share mtile
    const int mtile = wg >> 2;                   //  -> A slab L2-shared per XCD

    const int tid  = threadIdx.x;
    const int lane = tid & 63, wid = tid >> 6;
    const int wr = wid >> 2, wc = wid & 3;
    const int qq = lane >> 4, l15 = lane & 15;
    const int l15s = l15 ^ (2 * qq);             // read-side bank swizzle
    const int rA = wr * 16 + l15s;
    const int rB = wc * 16 + l15s;

    f32x4 acc[8][4] = {};
    half8 a[4][2], b0[2][2], b1[2][2];
    f32x4 aSt[8];

    // A staging geometry: instr p covers rows p*32 + (tid>>4) (4 rows x 16
    // lanes x 16 B contiguous per wave-instr = ideal coalescing);
    // lane covers cols l16*4..+4 of the 64-wide K-slab.
    const int arow0 = tid >> 4;                  // 0..31
    const int l16   = tid & 15;
    const int qw    = l16 >> 1, kh2 = l16 & 1;   // k-octet, low/high half4
    const float* agp = encA + (((size_t)(mtile * 256 + arow0)) << 10) + l16 * 4;

    const size_t bbase = (size_t)et * 32 * 8192;
    const int uoff = tid * 8;                    // per-thread 16B within chunk

    auto issueA = [&](int T) {
        const float* gp = agp + T * 64;
#pragma unroll
        for (int p = 0; p < 8; ++p)
            aSt[p] = *(const f32x4*)(gp + ((size_t)p << 15));   // p*32 rows
    };
    auto writeA = [&](int Tn) {
        const int base = (Tn & 1) << 14;         // A slot base (halfwords)
#pragma unroll
        for (int p = 0; p < 8; ++p) {
            const int r  = p * 32 + arow0;
            const int h  = r >> 7, lr = r & 127;
            const int lr2 = lr ^ (2 * (qw & 3)); // bank swizzle (matches RD_A)
            pk2 c0 = __builtin_amdgcn_cvt_pkrtz(aSt[p][0], aSt[p][1]);
            pk2 c1 = __builtin_amdgcn_cvt_pkrtz(aSt[p][2], aSt[p][3]);
            half4 hh; hh[0] = c0[0]; hh[1] = c0[1]; hh[2] = c1[0]; hh[3] = c1[1];
            *(half4*)&lds[base + h * 8192 + (qw * 128 + lr2) * 8 + kh2 * 4] = hh;
        }
    };
    auto stB = [&](int T, int h) {
        const _Float16* gp = W1TT + bbase + ((size_t)(T * 2 + h) << 13) + uoff;
        _Float16* lp = lds + (32768 + (((T & 1) * 2 + h) << 13) + (wid << 9));
        __builtin_amdgcn_global_load_lds((const GLOBAL_AS void*)gp,
                                         (LDS_AS void*)lp, 16, 0, 0);
        __builtin_amdgcn_global_load_lds((const GLOBAL_AS void*)(gp + 4096),
                                         (LDS_AS void*)(lp + 4096), 16, 0, 0);
    };

    // LDS bases (halfword units): tile slot = T&1.
    // A: slot0 h0=0, h1=8192 ; slot1 h0=16384, h1=24576.  B: +32768 each.

    // prologue: stage tile 0 (A via reg path, B via global_load_lds)
    issueA(0); stB(0, 0); stB(0, 1);
    VM(4);                                       // A8 landed (B4 outstanding)
    writeA(0);
    VM(0); LGKM(0);
    BAR;

#pragma unroll 2
    for (int T = 0; T < 16; ++T) {
        const int As  = (T & 1) << 14;           // A slot base (halfwords)
        const int Bs2 = 32768 + ((T & 1) << 14); // B slot base
        const bool s = (T < 15);

        // staging for tile T+1 first: maximizes in-flight slack
        if (s) { issueA(T + 1); stB(T + 1, 0); stB(T + 1, 1); }

        // tile T compute with counted-lgkm quadrant overlap
        RD_A(a, As);                 // 8 ds_read_b128 (rows 0..127)
        RD_B(b0, Bs2);               // 4
        RD_B(b1, Bs2 + 8192);        // 4
        LGKM(4);                     // a + b0 resident (b1 draining)
        PRIO1; MFMAQ(a, b0, 0, 0); PRIO0;
        LGKM(0);                     // b1 resident
        PRIO1; MFMAQ(a, b1, 0, 2); PRIO0;
        RD_A(a, As + 8192);          // rows 128..255 (WAR on a: safe, q2 issued)
        LGKM(0);
        PRIO1; MFMAQ(a, b0, 4, 0); MFMAQ(a, b1, 4, 2); PRIO0;

        if (s) { VM(4); writeA(T + 1); }         // A regs landed ~2000 cyc ago
        VM(0); LGKM(0);                          // B landed; ds_writes retired
        BAR;                                     // slot T&1 free; T+1 readable
    }

    // ---- epilogue: tanh(c + dec) * vt, reduce over this block's 256 cols ----
    const int b = mtile >> 3;                    // 8 mtiles per batch row
    float vtv[4], dcv[4];
#pragma unroll
    for (int nf = 0; nf < 4; ++nf) {
        int e = et * 256 + (nf >> 1) * 128 + (nf & 1) * 64 + wc * 16 + l15;
        vtv[nf] = vt[e];
        dcv[nf] = dec[b * Dd + e];
    }
    float* usum = (float*)lds;   // [4 wc][256 rows]; all staging drained
#pragma unroll
    for (int hm = 0; hm < 8; ++hm) {
        const int h = hm >> 2, mq = hm & 3;
#pragma unroll
        for (int r = 0; r < 4; ++r) {
            float sv = 0.f;
#pragma unroll
            for (int nf = 0; nf < 4; ++nf) {
                float x  = acc[hm][nf][r] + dcv[nf];
                float ex = __expf(2.f * x);
                sv += (1.f - 2.f * __builtin_amdgcn_rcpf(ex + 1.f)) * vtv[nf];
            }
#pragma unroll
            for (int off = 1; off < 16; off <<= 1) sv += __shfl_xor(sv, off, 16);
            if (l15 == 0)
                usum[wc * 256 + h * 128 + mq * 32 + wr * 16 + qq * 4 + r] = sv;
        }
    }
    __syncthreads();
    if (tid < 256) {
        float v = usum[tid] + usum[256 + tid] + usum[512 + tid] + usum[768 + tid];
        u_part[(size_t)et * M + (size_t)mtile * 256 + tid] = v;
    }
}

// ---------------------------------------------------------------------------
// Kernel 4: masked log-softmax over N=2048 per batch row (4 partial slices).
// ---------------------------------------------------------------------------
__global__ void softmax_k(const float* __restrict__ up, const int* __restrict__ mask,
                          float* __restrict__ out) {
    __shared__ float red[8];
    int b = blockIdx.x, tid = threadIdx.x;
    float l[8];
#pragma unroll
    for (int i = 0; i < 8; ++i) {
        int n = i * 256 + tid;
        float s = up[(size_t)b * Nn + n];
#pragma unroll
        for (int et = 1; et < 4; ++et) s += up[(size_t)et * M + (size_t)b * Nn + n];
        l[i] = s + (mask[b * Nn + n] ? 0.f : -103.278931f);  // ln(2^-149)
    }
    float m = l[0];
#pragma unroll
    for (int i = 1; i < 8; ++i) m = fmaxf(m, l[i]);
#pragma unroll
    for (int o = 32; o >= 1; o >>= 1) m = fmaxf(m, __shfl_xor(m, o, 64));
    if ((tid & 63) == 0) red[tid >> 6] = m;
    __syncthreads();
    m = fmaxf(fmaxf(red[0], red[1]), fmaxf(red[2], red[3]));
    float s = 0.f;
#pragma unroll
    for (int i = 0; i < 8; ++i) s += expf(l[i] - m);
#pragma unroll
    for (int o = 32; o >= 1; o >>= 1) s += __shfl_xor(s, o, 64);
    if ((tid & 63) == 0) red[4 + (tid >> 6)] = s;
    __syncthreads();
    float lse = m + logf(red[4] + red[5] + red[6] + red[7]);
#pragma unroll
    for (int i = 0; i < 8; ++i)
        out[(size_t)b * Nn + i * 256 + tid] = l[i] - lse;
}

// ---------------------------------------------------------------------------
extern "C" void kernel_launch(void* const* d_in, const int* in_sizes, int n_in,
                              void* d_out, int out_size, void* d_ws, size_t ws_size,
                              hipStream_t stream) {
    const float* encoded = (const float*)d_in[0];
    const float* dstate  = (const float*)d_in[1];
    const int*   mask    = (const int*)d_in[2];
    const float* W1      = (const float*)d_in[3];
    const float* W2      = (const float*)d_in[4];
    const float* vt      = (const float*)d_in[5];
    float* out = (float*)d_out;

    // ws layout: u_part (1 MiB) | dec (128 KB) | W1TT (2 MiB)   (~3.2 MB)
    char* ws = (char*)d_ws;
    float*    u_part = (float*)ws;
    float*    dec    = (float*)(ws + (size_t)4 * M * 4);
    _Float16* W1TT   = (_Float16*)(ws + (size_t)4 * M * 4 + (size_t)Bb * Dd * 4);

    static bool attr_done = false;
    if (!attr_done) {
        hipFuncSetAttribute(reinterpret_cast<const void*>(gemm8),
                            hipFuncAttributeMaxDynamicSharedMemorySize, 131072);
        attr_done = true;
    }

    prep_w1<<<512, 256, 0, stream>>>(W1, W1TT);
    dec_kernel<<<dim3(32, 16), 256, 0, stream>>>(dstate, W2, dec);
    gemm8<<<1024, 512, 131072, stream>>>(encoded, W1TT, dec, vt, u_part);
    softmax_k<<<32, 256, 0, stream>>>(u_part, mask, out);
}

// Round 7
// 523.724 us; speedup vs baseline: 1.2662x; 1.0016x over previous
//
#include <hip/hip_runtime.h>

typedef _Float16 half8 __attribute__((ext_vector_type(8)));
typedef _Float16 half4 __attribute__((ext_vector_type(4)));
typedef __fp16   pk2   __attribute__((ext_vector_type(2)));
typedef float    f32x4 __attribute__((ext_vector_type(4)));

#define GLOBAL_AS __attribute__((address_space(1)))
#define LDS_AS    __attribute__((address_space(3)))

static constexpr int Bb = 32;
static constexpr int Nn = 2048;
static constexpr int Dd = 1024;
static constexpr int M  = Bb * Nn;   // 65536 rows of the big GEMM

// ---------------------------------------------------------------------------
// B layout (prep_w1 -> gemm8): unchanged chunk format, staged linearly by
// global_load_lds; bank swizzle pre-baked into the GLOBAL image (both-sides
// rule). W1TT chunks: [et(4)][t(16)][h(2)].
// A is read as f32 directly from `encoded` (prep_enc pass deleted). gemm8
// reg-stages A (global_load_dwordx4 -> cvt_pkrtz -> ds_write_b64) into a
// ROW-MAJOR swizzled image: half4 unit (row,kc) at row*16 + (kc ^ ((row&7)*2)).
//  - write: each 16-lane group writes one row = 16 units = 128 B = every bank
//    exactly once -> conflict-free (r6's layout hit 8-bank aliasing, 4.2M cyc).
//  - read:  even XOR keeps unit pairs adjacent (b128 legal); 2-way bank
//    aliasing only (free per m136).
// ---------------------------------------------------------------------------

// Kernel 1a: pack W1 (f32 [d][e]) -> swizzled f16 chunks.
__global__ void prep_w1(const float* __restrict__ W1, _Float16* __restrict__ W1TT) {
    int g = blockIdx.x * 256 + threadIdx.x;   // 131072 half8 units
    int chunk = g >> 10;                      // et*32 + t*2 + h
    int u = g & 1023;
    int q = u >> 7, sc = u & 127;
    int cl = sc ^ (2 * (q & 3));
    int et = chunk >> 5, t = (chunk >> 1) & 15, h = chunk & 1;
    int e  = et * 256 + h * 128 + cl;
    int k0 = t * 64 + q * 8;
    half8 hh;
#pragma unroll
    for (int j = 0; j < 8; ++j)
        hh[j] = (_Float16)W1[(size_t)(k0 + j) * Dd + e];
    *(half8*)(W1TT + (size_t)g * 8) = hh;
}

// ---------------------------------------------------------------------------
// Kernel 2: dec[b][e] = decoder_state[b] @ W2   (32x1024)
// ---------------------------------------------------------------------------
__global__ void dec_kernel(const float* __restrict__ ds, const float* __restrict__ W2,
                           float* __restrict__ dec) {
    __shared__ float part[4][64];
    int b = blockIdx.x, ech = blockIdx.y;
    int tid = threadIdx.x;
    int e = ech * 64 + (tid & 63);
    int dc = tid >> 6;
    float acc = 0.f;
#pragma unroll 4
    for (int d = dc * 256; d < dc * 256 + 256; ++d)
        acc += ds[b * Dd + d] * W2[(size_t)d * Dd + e];
    part[dc][tid & 63] = acc;
    __syncthreads();
    if (tid < 64)
        dec[b * Dd + e] = part[0][tid] + part[1][tid] + part[2][tid] + part[3][tid];
}

// ---------------------------------------------------------------------------
// Kernel 3: 256x256 tile, 8 waves, fused f32->f16 A-staging.
// Per K-tile: issue 8 global_load_dwordx4 (A f32 -> regs, 4 rows x 256 B per
// instr = ideal coalescing) + 4 global_load_lds (B f16) for tile T+1; issue
// tile T's 16 ds_read_b128; counted-lgkm quadrant overlap:
//   LGKM(4) q1(a.b0) | LGKM(0) q2(a.b1) | reload a<-h1 | LGKM(0) q3 q4
// then VM(4) [A regs landed] -> cvt_pkrtz + 8 conflict-free ds_write_b64 ->
// VM(0) [B landed] -> LGKM(0) -> BAR. One barrier per K-tile.
// __launch_bounds__(512, 2): LDS already limits to 1 wg/CU (2 waves/EU), so
// raise the VGPR cap to 256 and kill r6's 14 MB/dispatch scratch spill.
// ---------------------------------------------------------------------------
#define BAR     asm volatile("s_barrier" ::: "memory")
#define LGKM(n) asm volatile("s_waitcnt lgkmcnt(" #n ")" ::: "memory")
#define VM(n)   asm volatile("s_waitcnt vmcnt(" #n ")" ::: "memory")
#define PRIO1   __builtin_amdgcn_s_setprio(1)
#define PRIO0   __builtin_amdgcn_s_setprio(0)

// A image: half4 unit (row,kc) -> halfword addr (row*16 + (kc ^ ((row&7)*2)))*4
#define RD_A(dst, base) do { _Pragma("unroll") \
  for (int ks = 0; ks < 2; ++ks) { \
    _Pragma("unroll") for (int m2 = 0; m2 < 4; ++m2) { \
      const int row_ = m2 * 32 + rA; \
      const int kc0_ = (ks * 4 + qq) * 2; \
      dst[m2][ks] = *(const half8*)&lds[(base) + (row_ * 16 + (kc0_ ^ rxa)) * 4]; \
    } } } while (0)

#define RD_B(dst, base) do { _Pragma("unroll") \
  for (int ks = 0; ks < 2; ++ks) { const int qb = ((ks * 4 + qq) * 128) * 8; \
    _Pragma("unroll") for (int j2 = 0; j2 < 2; ++j2) \
      dst[j2][ks] = *(const half8*)&lds[(base) + qb + (j2 * 64 + rB) * 8]; } } while (0)

#define MFMAQ(A_, B_, ro, co) do { \
  _Pragma("unroll") for (int m2 = 0; m2 < 4; ++m2) \
  _Pragma("unroll") for (int j2 = 0; j2 < 2; ++j2) { \
    acc[(ro) + m2][(co) + j2] = __builtin_amdgcn_mfma_f32_16x16x32_f16( \
        A_[m2][0], B_[j2][0], acc[(ro) + m2][(co) + j2], 0, 0, 0); \
    acc[(ro) + m2][(co) + j2] = __builtin_amdgcn_mfma_f32_16x16x32_f16( \
        A_[m2][1], B_[j2][1], acc[(ro) + m2][(co) + j2], 0, 0, 0); } } while (0)

__global__ __launch_bounds__(512, 2) void gemm8(
    const float* __restrict__ encA, const _Float16* __restrict__ W1TT,
    const float* __restrict__ dec, const float* __restrict__ vt,
    float* __restrict__ u_part)          // [4][65536]
{
    extern __shared__ _Float16 lds[];    // 65536 halfs = 128 KB

    const int g  = blockIdx.x;                   // 0..1023
    const int wg = (g & 7) * 128 + (g >> 3);     // XCD-chunked swizzle (1024%8==0)
    const int et    = wg & 3;                    // 4 consecutive wg share mtile
    const int mtile = wg >> 2;                   //  -> A slab L2-shared per XCD

    const int tid  = threadIdx.x;
    const int lane = tid & 63, wid = tid >> 6;
    const int wr = wid >> 2, wc = wid & 3;
    const int qq = lane >> 4, l15 = lane & 15;
    const int l15s = l15 ^ (2 * qq);             // B read-side bank swizzle
    const int rA = wr * 16 + l15;                // A rows: plain (layout swizzles)
    const int rxa = (l15 & 7) * 2;               // A read XOR (row&7)*2
    const int rB = wc * 16 + l15s;

    f32x4 acc[8][4] = {};
    half8 a[4][2], b0[2][2], b1[2][2];
    f32x4 aSt[8];

    // A staging geometry: instr p covers rows p*32 + (tid>>4); lane covers
    // cols l16*4..+4 of the 64-wide K-slab (4 rows x 256 B contiguous/instr).
    const int arow0 = tid >> 4;                  // 0..31
    const int l16   = tid & 15;
    const float* agp = encA + (((size_t)(mtile * 256 + arow0)) << 10) + l16 * 4;

    const size_t bbase = (size_t)et * 32 * 8192;
    const int uoff = tid * 8;                    // per-thread 16B within chunk

    auto issueA = [&](int T) {
        const float* gp = agp + T * 64;
#pragma unroll
        for (int p = 0; p < 8; ++p)
            aSt[p] = *(const f32x4*)(gp + ((size_t)p << 15));   // p*32 rows
    };
    auto writeA = [&](int Tn) {
        const int base = (Tn & 1) << 14;         // A slot base (halfwords)
#pragma unroll
        for (int p = 0; p < 8; ++p) {
            const int rf = p * 32 + arow0;
            const int h  = rf >> 7, row = rf & 127;
            pk2 c0 = __builtin_amdgcn_cvt_pkrtz(aSt[p][0], aSt[p][1]);
            pk2 c1 = __builtin_amdgcn_cvt_pkrtz(aSt[p][2], aSt[p][3]);
            half4 hh; hh[0] = c0[0]; hh[1] = c0[1]; hh[2] = c1[0]; hh[3] = c1[1];
            *(half4*)&lds[base + h * 8192
                          + (row * 16 + (l16 ^ ((row & 7) * 2))) * 4] = hh;
        }
    };
    auto stB = [&](int T, int h) {
        const _Float16* gp = W1TT + bbase + ((size_t)(T * 2 + h) << 13) + uoff;
        _Float16* lp = lds + (32768 + (((T & 1) * 2 + h) << 13) + (wid << 9));
        __builtin_amdgcn_global_load_lds((const GLOBAL_AS void*)gp,
                                         (LDS_AS void*)lp, 16, 0, 0);
        __builtin_amdgcn_global_load_lds((const GLOBAL_AS void*)(gp + 4096),
                                         (LDS_AS void*)(lp + 4096), 16, 0, 0);
    };

    // LDS bases (halfword units): tile slot = T&1.
    // A: slot0 h0=0, h1=8192 ; slot1 h0=16384, h1=24576.  B: +32768 each.

    // prologue: stage tile 0 (A via reg path, B via global_load_lds)
    issueA(0); stB(0, 0); stB(0, 1);
    VM(4);                                       // A8 landed (B4 outstanding)
    writeA(0);
    VM(0); LGKM(0);
    BAR;

#pragma unroll 2
    for (int T = 0; T < 16; ++T) {
        const int As  = (T & 1) << 14;           // A slot base (halfwords)
        const int Bs2 = 32768 + ((T & 1) << 14); // B slot base
        const bool s = (T < 15);

        // staging for tile T+1 first: maximizes in-flight slack
        if (s) { issueA(T + 1); stB(T + 1, 0); stB(T + 1, 1); }

        // tile T compute with counted-lgkm quadrant overlap
        RD_A(a, As);                 // 8 ds_read_b128 (rows 0..127)
        RD_B(b0, Bs2);               // 4
        RD_B(b1, Bs2 + 8192);        // 4
        LGKM(4);                     // a + b0 resident (b1 draining)
        PRIO1; MFMAQ(a, b0, 0, 0); PRIO0;
        LGKM(0);                     // b1 resident
        PRIO1; MFMAQ(a, b1, 0, 2); PRIO0;
        RD_A(a, As + 8192);          // rows 128..255 (WAR on a: safe, q2 issued)
        LGKM(0);
        PRIO1; MFMAQ(a, b0, 4, 0); MFMAQ(a, b1, 4, 2); PRIO0;

        if (s) { VM(4); writeA(T + 1); }         // A regs landed ~2000 cyc ago
        VM(0); LGKM(0);                          // B landed; ds_writes retired
        BAR;                                     // slot T&1 free; T+1 readable
    }

    // ---- epilogue: tanh(c + dec) * vt, reduce over this block's 256 cols ----
    const int b = mtile >> 3;                    // 8 mtiles per batch row
    float vtv[4], dcv[4];
#pragma unroll
    for (int nf = 0; nf < 4; ++nf) {
        int e = et * 256 + (nf >> 1) * 128 + (nf & 1) * 64 + wc * 16 + l15;
        vtv[nf] = vt[e];
        dcv[nf] = dec[b * Dd + e];
    }
    float* usum = (float*)lds;   // [4 wc][256 rows]; all staging drained
#pragma unroll
    for (int hm = 0; hm < 8; ++hm) {
        const int h = hm >> 2, mq = hm & 3;
#pragma unroll
        for (int r = 0; r < 4; ++r) {
            float sv = 0.f;
#pragma unroll
            for (int nf = 0; nf < 4; ++nf) {
                float x  = acc[hm][nf][r] + dcv[nf];
                float ex = __expf(2.f * x);
                sv += (1.f - 2.f * __builtin_amdgcn_rcpf(ex + 1.f)) * vtv[nf];
            }
#pragma unroll
            for (int off = 1; off < 16; off <<= 1) sv += __shfl_xor(sv, off, 16);
            if (l15 == 0)
                usum[wc * 256 + h * 128 + mq * 32 + wr * 16 + qq * 4 + r] = sv;
        }
    }
    __syncthreads();
    if (tid < 256) {
        float v = usum[tid] + usum[256 + tid] + usum[512 + tid] + usum[768 + tid];
        u_part[(size_t)et * M + (size_t)mtile * 256 + tid] = v;
    }
}

// ---------------------------------------------------------------------------
// Kernel 4: masked log-softmax over N=2048 per batch row (4 partial slices).
// ---------------------------------------------------------------------------
__global__ void softmax_k(const float* __restrict__ up, const int* __restrict__ mask,
                          float* __restrict__ out) {
    __shared__ float red[8];
    int b = blockIdx.x, tid = threadIdx.x;
    float l[8];
#pragma unroll
    for (int i = 0; i < 8; ++i) {
        int n = i * 256 + tid;
        float s = up[(size_t)b * Nn + n];
#pragma unroll
        for (int et = 1; et < 4; ++et) s += up[(size_t)et * M + (size_t)b * Nn + n];
        l[i] = s + (mask[b * Nn + n] ? 0.f : -103.278931f);  // ln(2^-149)
    }
    float m = l[0];
#pragma unroll
    for (int i = 1; i < 8; ++i) m = fmaxf(m, l[i]);
#pragma unroll
    for (int o = 32; o >= 1; o >>= 1) m = fmaxf(m, __shfl_xor(m, o, 64));
    if ((tid & 63) == 0) red[tid >> 6] = m;
    __syncthreads();
    m = fmaxf(fmaxf(red[0], red[1]), fmaxf(red[2], red[3]));
    float s = 0.f;
#pragma unroll
    for (int i = 0; i < 8; ++i) s += expf(l[i] - m);
#pragma unroll
    for (int o = 32; o >= 1; o >>= 1) s += __shfl_xor(s, o, 64);
    if ((tid & 63) == 0) red[4 + (tid >> 6)] = s;
    __syncthreads();
    float lse = m + logf(red[4] + red[5] + red[6] + red[7]);
#pragma unroll
    for (int i = 0; i < 8; ++i)
        out[(size_t)b * Nn + i * 256 + tid] = l[i] - lse;
}

// ---------------------------------------------------------------------------
extern "C" void kernel_launch(void* const* d_in, const int* in_sizes, int n_in,
                              void* d_out, int out_size, void* d_ws, size_t ws_size,
                              hipStream_t stream) {
    const float* encoded = (const float*)d_in[0];
    const float* dstate  = (const float*)d_in[1];
    const int*   mask    = (const int*)d_in[2];
    const float* W1      = (const float*)d_in[3];
    const float* W2      = (const float*)d_in[4];
    const float* vt      = (const float*)d_in[5];
    float* out = (float*)d_out;

    // ws layout: u_part (1 MiB) | dec (128 KB) | W1TT (2 MiB)   (~3.2 MB)
    char* ws = (char*)d_ws;
    float*    u_part = (float*)ws;
    float*    dec    = (float*)(ws + (size_t)4 * M * 4);
    _Float16* W1TT   = (_Float16*)(ws + (size_t)4 * M * 4 + (size_t)Bb * Dd * 4);

    static bool attr_done = false;
    if (!attr_done) {
        hipFuncSetAttribute(reinterpret_cast<const void*>(gemm8),
                            hipFuncAttributeMaxDynamicSharedMemorySize, 131072);
        attr_done = true;
    }

    prep_w1<<<512, 256, 0, stream>>>(W1, W1TT);
    dec_kernel<<<dim3(32, 16), 256, 0, stream>>>(dstate, W2, dec);
    gemm8<<<1024, 512, 131072, stream>>>(encoded, W1TT, dec, vt, u_part);
    softmax_k<<<32, 256, 0, stream>>>(u_part, mask, out);
}